// Round 4
// baseline (332.045 us; speedup 1.0000x reference)
//
#include <hip/hip_runtime.h>
#include <math.h>

#define BATCH 128
#define S 50
#define D 128
#define SAMPLE 12

typedef __attribute__((ext_vector_type(8))) short short8v;
typedef __attribute__((ext_vector_type(4))) float f32x4;
typedef unsigned short u16;

__device__ __forceinline__ float leakyf(float x) { return x >= 0.f ? x : 0.2f * x; }
__device__ __forceinline__ u16 f2bf(float f) {
    union { float f; unsigned u; } v; v.f = f;
    unsigned u = v.u;
    return (u16)((u + 0x7FFFu + ((u >> 16) & 1u)) >> 16);  // RNE
}
__device__ __forceinline__ float bf2f(u16 h) {
    union { float f; unsigned u; } v; v.u = ((unsigned)h) << 16; return v.f;
}

// ---------------------------------------------------------------------------
// setup1: session + n1 (1-hop indices) + nw0 (1-hop weights)
// ---------------------------------------------------------------------------
__global__ __launch_bounds__(256) void setup1_kernel(
    const int* __restrict__ item, const int* __restrict__ mask,
    const int* __restrict__ inputs, const int* __restrict__ adj_all,
    const float* __restrict__ num_weight, const float* __restrict__ emb,
    float* __restrict__ session, int* __restrict__ n1, float* __restrict__ nw0)
{
    const int bx = blockIdx.x, t = threadIdx.x;
    if (bx < BATCH) {
        if (t < 128) {
            float num = 0.f, den = 0.f;
            for (int s = 0; s < S; ++s) {
                float m = (float)mask[bx * S + s];
                num += m * emb[item[bx * S + s] * D + t];
                den += m;
            }
            session[bx * D + t] = num / den;
        }
    } else {
        int idx = (bx - BATCH) * 256 + t;
        if (idx < BATCH * 600) {
            int b = idx / 600, j = idx % 600;
            int node = inputs[b * S + j / SAMPLE];
            n1[idx]  = adj_all[node * SAMPLE + j % SAMPLE];
            nw0[idx] = num_weight[node * SAMPLE + j % SAMPLE];
        }
    }
}

// ---------------------------------------------------------------------------
// prep2: emb->bf16, sessW1 bf16, W3T bf16, n2/nw1 (2-hop tables; needs n1)
// ---------------------------------------------------------------------------
__global__ __launch_bounds__(256) void prep2_kernel(
    const float* __restrict__ emb, const float* __restrict__ w1,
    const float* __restrict__ w3, const float* __restrict__ session,
    const int* __restrict__ adj_all, const float* __restrict__ num_weight,
    const int* __restrict__ n1,
    u16* __restrict__ emb_bf, u16* __restrict__ sw1, u16* __restrict__ w3t,
    int* __restrict__ n2, float* __restrict__ nw1)
{
    const int bx = blockIdx.x, t = threadIdx.x;
    if (bx < 2500) {                       // embedding -> bf16, 8 elems/thread
        int idx = bx * 256 + t;
        const float4* src = reinterpret_cast<const float4*>(emb) + (size_t)idx * 2;
        float4 a = src[0], c = src[1];
        u16 o[8] = {f2bf(a.x), f2bf(a.y), f2bf(a.z), f2bf(a.w),
                    f2bf(c.x), f2bf(c.y), f2bf(c.z), f2bf(c.w)};
        *reinterpret_cast<uint4*>(emb_bf + (size_t)idx * 8) = *reinterpret_cast<uint4*>(o);
    } else if (bx < 2756) {                // sessW1: block = (hop,b)
        int id = bx - 2500, hop = id >> 7, b = id & 127;
        const float* w1s = w1 + hop * 129 * 128;
        const float* se = session + b * 128;
        int n = t >> 1, kh = (t & 1) * 64;
        u16* dst = sw1 + (((size_t)(hop * 128 + b) * 128 + n) * 128) + kh;
        for (int kq = 0; kq < 64; kq += 8) {
            u16 o[8];
            #pragma unroll
            for (int e = 0; e < 8; ++e) { int k = kh + kq + e; o[e] = f2bf(w1s[k * 128 + n] * se[k]); }
            *reinterpret_cast<uint4*>(dst + kq) = *reinterpret_cast<uint4*>(o);
        }
    } else if (bx < 2788) {                // W3T [hop][n][k]
        int j = (bx - 2756) * 256 + t;     // < 8192
        int hop = j >> 12, r = j & 4095, n = r >> 5, k0 = (r & 31) * 8;
        const float* w3s = w3 + hop * 256 * 128;
        u16 o[8];
        #pragma unroll
        for (int e = 0; e < 8; ++e) o[e] = f2bf(w3s[(k0 + e) * 128 + n]);
        *reinterpret_cast<uint4*>(w3t + ((size_t)hop * 128 + n) * 256 + k0) = *reinterpret_cast<uint4*>(o);
    } else {                               // n2 / nw1 (2-hop)
        int idx = (bx - 2788) * 256 + t;
        if (idx < BATCH * 7200) {
            int b = idx / 7200, j = idx % 7200;
            int node = n1[b * 600 + j / SAMPLE];
            n2[idx]  = adj_all[node * SAMPLE + j % SAMPLE];
            nw1[idx] = num_weight[node * SAMPLE + j % SAMPLE];
        }
    }
}

// ---------------------------------------------------------------------------
// Fused main kernel. 8 l-rows (96 samples) per block, 4 waves.
// PATH 0, grid (83,128): bx<75 -> mode1 -> out1; bx 75..81 -> mode0 -> out0;
//                        bx==82 -> local_agg -> d_out.
// PATH 2, grid (7,128):  mode2 (self=out0, neigh=out1, hop1) += d_out.
//
// nvL/selfL are stored in MFMA-fragment order (lane-linear): LDS addr16 =
// (mt*4+kk)*64 + lane; the row permutation  m = (cn>>2)*24 + mt*4 + (cn&3)
// makes each accumulator lane own 24 consecutive m's => each l-group's 12
// rows live in one cg group => softmax-weighted PV combine is register-only.
// ---------------------------------------------------------------------------
template <int PATH>
__global__ __launch_bounds__(256, 4) void main_kernel(
    const int* __restrict__ inputs, const int* __restrict__ adj,
    const float* __restrict__ emb, const float* __restrict__ a_local,
    const int* __restrict__ n1, const int* __restrict__ n2,
    const float* __restrict__ nw0, const float* __restrict__ nw1,
    const u16* __restrict__ emb_bf, const u16* __restrict__ sw1,
    const float* __restrict__ w1, const float* __restrict__ w2,
    const u16* __restrict__ w3t,
    const u16* __restrict__ in0, const u16* __restrict__ in1,
    u16* __restrict__ o0, u16* __restrict__ o1, float* __restrict__ outf)
{
    __shared__ __align__(16) char smem[37664];
    const int b = blockIdx.y;
    const int t = threadIdx.x;
    const int bx = blockIdx.x;

    if (PATH == 0 && bx == 82) {
        // ------------------- local aggregation -------------------
        float (*h)[D]     = (float(*)[D])smem;            // 25600 B
        float (*al)[D]    = (float(*)[D])(smem + 25600);  // 2048 B
        float (*alpha)[S] = (float(*)[S])(smem + 27648);  // 10000 B

        for (int idx = t; idx < S * D; idx += 256) {
            int i = idx / D, d = idx % D;
            h[i][d] = emb[inputs[b * S + i] * D + d];
        }
        for (int idx = t; idx < 4 * D; idx += 256) al[idx / D][idx % D] = a_local[idx];
        __syncthreads();

        for (int p = t; p < S * S; p += 256) {
            int i = p / S, j = p % S;
            int a = adj[b * S * S + p];
            float v = -9e15f;
            if (a >= 1 && a <= 4) {
                const float* ak = al[a - 1];
                float dot = 0.f;
                #pragma unroll 4
                for (int d = 0; d < D; ++d) dot += h[i][d] * h[j][d] * ak[d];
                v = leakyf(dot);
            }
            alpha[i][j] = v;
        }
        __syncthreads();

        if (t < S) {
            float m = -INFINITY;
            for (int j = 0; j < S; ++j) m = fmaxf(m, alpha[t][j]);
            float ssum = 0.f;
            for (int j = 0; j < S; ++j) { float e = expf(alpha[t][j] - m); alpha[t][j] = e; ssum += e; }
            float inv = 1.f / ssum;
            for (int j = 0; j < S; ++j) alpha[t][j] *= inv;
        }
        __syncthreads();

        for (int idx = t; idx < S * D; idx += 256) {
            int i = idx / D, d = idx % D;
            float acc = 0.f;
            #pragma unroll 5
            for (int j = 0; j < S; ++j) acc += alpha[i][j] * h[j][d];
            outf[b * S * D + idx] = acc;
        }
        return;
    }

    // ------------------- global aggregation -------------------
    int mode, l0, L, Lm, hop;
    const u16 *nsrc, *ssrc;
    const int* idxTab; const float* nwTab;
    u16* outb;
    if (PATH == 2)    { mode = 2; l0 = bx * 8;        L = 50;  Lm = 600;  nsrc = in1;    ssrc = in0;    idxTab = nullptr; nwTab = nw0; outb = nullptr; hop = 1; }
    else if (bx < 75) { mode = 1; l0 = bx * 8;        L = 600; Lm = 7200; nsrc = emb_bf; ssrc = emb_bf; idxTab = n2;      nwTab = nw1; outb = o1;      hop = 0; }
    else              { mode = 0; l0 = (bx - 75) * 8; L = 50;  Lm = 600;  nsrc = emb_bf; ssrc = emb_bf; idxTab = n1;      nwTab = nw0; outb = o0;      hop = 0; }

    u16* nvL   = (u16*)smem;                              // 1536 slots * 16B = 24576
    u16* selfL = (u16*)(smem + 24576);                    // 256 slots * 16B = 4096
    float (*score_w)[96] = (float(*)[96])(smem + 28672);  // 1536
    float* score = (float*)(smem + 30208);                // 384
    float* nwgtL = (float*)(smem + 30592);                // 384

    const u16*   sw1b   = sw1 + (size_t)(hop * 128 + b) * 16384;
    const float* w1last = w1 + hop * 129 * 128 + 128 * 128;
    const float* w2h    = w2 + hop * 128;
    const u16*   w3th   = w3t + hop * 32768;

    const int lane = t & 63, wv = t >> 6, cn = lane & 15, cg = lane >> 4;
    const int nc0 = (2 * wv) * 16 + cn, nc1 = (2 * wv + 1) * 16 + cn;

    // ---- stage neighbor rows, fragment-order (lane-linear LDS => no bank
    //      conflicts); row permutation folded into the global gather addr ----
    #pragma unroll
    for (int i = 0; i < 6; ++i) {
        int slot = i * 256 + t;                     // 0..1535
        int mt = slot >> 8, kk = (slot >> 6) & 3;
        int ln2 = slot & 63, cg2 = ln2 >> 4, cn2 = ln2 & 15;
        int gm = l0 * 12 + (cn2 >> 2) * 24 + mt * 4 + (cn2 & 3);
        int gmc = (gm < Lm) ? gm : 0;
        int row = (PATH == 2) ? (b * 600 + gmc) : idxTab[b * Lm + gmc];
        int chunk = kk * 4 + cg2;
        uint4 v = *reinterpret_cast<const uint4*>(nsrc + (size_t)row * 128 + chunk * 8);
        *reinterpret_cast<uint4*>(nvL + slot * 8) = v;
    }
    // ---- stage self rows: A row i holds self l = 2*(i>>2) + ((i>>1)&1) ----
    {
        int kk = t >> 6, ln2 = t & 63, cg2 = ln2 >> 4, i2 = ln2 & 15;
        int l = 2 * (i2 >> 2) + ((i2 >> 1) & 1);
        int lg = l0 + l; if (lg >= L) lg = 0;
        int srow;
        if (PATH == 2) srow = b * 50 + lg;
        else           srow = (mode == 1) ? n1[b * 600 + lg] : inputs[b * S + lg];
        uint4 v = *reinterpret_cast<const uint4*>(ssrc + (size_t)srow * 128 + (kk * 4 + cg2) * 8);
        *reinterpret_cast<uint4*>(selfL + t * 8) = v;
    }
    if (t < 96) {
        int gm = l0 * 12 + t;
        nwgtL[t] = (gm < Lm) ? nwTab[b * Lm + gm] : 0.f;
    }
    __syncthreads();

    // ---- GEMM1: z[96,128] = nv @ sessW1 ----
    f32x4 acc[6][2];
    #pragma unroll
    for (int mt = 0; mt < 6; ++mt) {
        acc[mt][0] = (f32x4){0.f, 0.f, 0.f, 0.f};
        acc[mt][1] = (f32x4){0.f, 0.f, 0.f, 0.f};
    }
    #pragma unroll
    for (int kk = 0; kk < 4; ++kk) {
        int kb = kk * 32 + cg * 8;
        short8v b0 = *reinterpret_cast<const short8v*>(sw1b + nc0 * 128 + kb);
        short8v b1 = *reinterpret_cast<const short8v*>(sw1b + nc1 * 128 + kb);
        #pragma unroll
        for (int mt = 0; mt < 6; ++mt) {
            short8v a = *reinterpret_cast<const short8v*>(nvL + ((mt * 4 + kk) * 64 + lane) * 8);
            acc[mt][0] = __builtin_amdgcn_mfma_f32_16x16x32_bf16(a, b0, acc[mt][0], 0, 0, 0);
            acc[mt][1] = __builtin_amdgcn_mfma_f32_16x16x32_bf16(a, b1, acc[mt][1], 0, 0, 0);
        }
    }

    // ---- score epilogue: K=129 rank-1 + leaky + @W2, reduce over n ----
    {
        float w2v0 = w2h[nc0], w2v1 = w2h[nc1];
        float w1l0 = w1last[nc0], w1l1 = w1last[nc1];
        #pragma unroll
        for (int mt = 0; mt < 6; ++mt) {
            #pragma unroll
            for (int r = 0; r < 4; ++r) {
                int m = cg * 24 + mt * 4 + r;
                float nw = nwgtL[m];
                float v = leakyf(acc[mt][0][r] + nw * w1l0) * w2v0 +
                          leakyf(acc[mt][1][r] + nw * w1l1) * w2v1;
                v += __shfl_xor(v, 1); v += __shfl_xor(v, 2);
                v += __shfl_xor(v, 4); v += __shfl_xor(v, 8);
                if (cn == 0) score_w[wv][m] = v;
            }
        }
    }
    __syncthreads();

    // ---- softmax over 12 samples per l ----
    if (t < 8) {
        float e[SAMPLE]; float mx = -INFINITY;
        #pragma unroll
        for (int s2 = 0; s2 < SAMPLE; ++s2) {
            int m = t * SAMPLE + s2;
            float v = score_w[0][m] + score_w[1][m] + score_w[2][m] + score_w[3][m];
            e[s2] = v; mx = fmaxf(mx, v);
        }
        float ssum = 0.f;
        #pragma unroll
        for (int s2 = 0; s2 < SAMPLE; ++s2) { e[s2] = expf(e[s2] - mx); ssum += e[s2]; }
        float inv = 1.f / ssum;
        #pragma unroll
        for (int s2 = 0; s2 < SAMPLE; ++s2) score[t * SAMPLE + s2] = e[s2] * inv;
    }
    __syncthreads();

    // ---- Y = nv @ W3b (reuse acc) + self @ W3a; combine with alpha in regs ----
    f32x4 accS0 = (f32x4){0.f, 0.f, 0.f, 0.f};
    f32x4 accS1 = (f32x4){0.f, 0.f, 0.f, 0.f};
    #pragma unroll
    for (int mt = 0; mt < 6; ++mt) {
        acc[mt][0] = (f32x4){0.f, 0.f, 0.f, 0.f};
        acc[mt][1] = (f32x4){0.f, 0.f, 0.f, 0.f};
    }
    #pragma unroll
    for (int kk = 0; kk < 4; ++kk) {
        int kb = kk * 32 + cg * 8;
        short8v by0 = *reinterpret_cast<const short8v*>(w3th + nc0 * 256 + 128 + kb);
        short8v by1 = *reinterpret_cast<const short8v*>(w3th + nc1 * 256 + 128 + kb);
        short8v bs0 = *reinterpret_cast<const short8v*>(w3th + nc0 * 256 + kb);
        short8v bs1 = *reinterpret_cast<const short8v*>(w3th + nc1 * 256 + kb);
        short8v aS = *reinterpret_cast<const short8v*>(selfL + (kk * 64 + lane) * 8);
        accS0 = __builtin_amdgcn_mfma_f32_16x16x32_bf16(aS, bs0, accS0, 0, 0, 0);
        accS1 = __builtin_amdgcn_mfma_f32_16x16x32_bf16(aS, bs1, accS1, 0, 0, 0);
        #pragma unroll
        for (int mt = 0; mt < 6; ++mt) {
            short8v a = *reinterpret_cast<const short8v*>(nvL + ((mt * 4 + kk) * 64 + lane) * 8);
            acc[mt][0] = __builtin_amdgcn_mfma_f32_16x16x32_bf16(a, by0, acc[mt][0], 0, 0, 0);
            acc[mt][1] = __builtin_amdgcn_mfma_f32_16x16x32_bf16(a, by1, acc[mt][1], 0, 0, 0);
        }
    }
    // alpha-weighted combine: lane's 24 rows are m = cg*24 + mt*4 + r,
    // l = cg*2 + (mt>=3) -- compile-time bucketing, no cross-lane ops.
    float P00 = 0.f, P01 = 0.f, P10 = 0.f, P11 = 0.f;
    #pragma unroll
    for (int mt = 0; mt < 6; ++mt) {
        #pragma unroll
        for (int r = 0; r < 4; ++r) {
            float al = score[cg * 24 + mt * 4 + r];
            if (mt < 3) { P00 += al * acc[mt][0][r]; P01 += al * acc[mt][1][r]; }
            else        { P10 += al * acc[mt][0][r]; P11 += al * acc[mt][1][r]; }
        }
    }
    // ---- relu + store: l = cg*2 + bucket; self rows r=0 (l even), r=2 (odd)
    {
        float v00 = fmaxf(P00 + accS0[0], 0.f);  // (l = cg*2,   n = nc0)
        float v01 = fmaxf(P01 + accS1[0], 0.f);  // (l = cg*2,   n = nc1)
        float v10 = fmaxf(P10 + accS0[2], 0.f);  // (l = cg*2+1, n = nc0)
        float v11 = fmaxf(P11 + accS1[2], 0.f);
        int lg0 = l0 + cg * 2, lg1 = lg0 + 1;
        if (PATH == 2) {
            if (lg0 < L) {
                float* p = outf + ((size_t)b * 50 + lg0) * 128;
                p[nc0] += v00; p[nc1] += v01;
            }
            if (lg1 < L) {
                float* p = outf + ((size_t)b * 50 + lg1) * 128;
                p[nc0] += v10; p[nc1] += v11;
            }
        } else {
            if (lg0 < L) {
                u16* p = outb + ((size_t)b * L + lg0) * 128;
                p[nc0] = f2bf(v00); p[nc1] = f2bf(v01);
            }
            if (lg1 < L) {
                u16* p = outb + ((size_t)b * L + lg1) * 128;
                p[nc0] = f2bf(v10); p[nc1] = f2bf(v11);
            }
        }
    }
}

// ---------------------------------------------------------------------------
extern "C" void kernel_launch(void* const* d_in, const int* in_sizes, int n_in,
                              void* d_out, int out_size, void* d_ws, size_t ws_size,
                              hipStream_t stream)
{
    const int*   inputs     = (const int*)d_in[0];
    const int*   adj        = (const int*)d_in[1];
    const int*   mask_item  = (const int*)d_in[2];
    const int*   item       = (const int*)d_in[3];
    const int*   adj_all    = (const int*)d_in[4];
    const float* num_weight = (const float*)d_in[5];
    const float* embedding  = (const float*)d_in[6];
    const float* a_local    = (const float*)d_in[7];
    const float* agg_w1     = (const float*)d_in[8];
    const float* agg_w2     = (const float*)d_in[9];
    const float* agg_w3     = (const float*)d_in[10];
    float* out = (float*)d_out;

    // workspace layout (16B aligned)
    char* w = (char*)d_ws;
    float* ws_session = (float*)(w);               //     65,536 B
    int*   ws_n1      = (int*)(w + 65536);         //    307,200 B
    float* ws_nw0     = (float*)(w + 372736);      //    307,200 B
    int*   ws_n2      = (int*)(w + 679936);        //  3,686,400 B
    float* ws_nw1     = (float*)(w + 4366336);     //  3,686,400 B
    u16*   ws_emb     = (u16*)(w + 8052736);       // 10,240,000 B
    u16*   ws_sw1     = (u16*)(w + 18292736);      //  8,388,608 B
    u16*   ws_w3t     = (u16*)(w + 26681344);      //    131,072 B
    u16*   ws_out0    = (u16*)(w + 26812416);      //  1,638,400 B
    u16*   ws_out1    = (u16*)(w + 28450816);      // 19,660,800 B (end ~45.9 MB)

    setup1_kernel<<<dim3(BATCH + 300), 256, 0, stream>>>(
        item, mask_item, inputs, adj_all, num_weight, embedding,
        ws_session, ws_n1, ws_nw0);
    prep2_kernel<<<dim3(6388), 256, 0, stream>>>(
        embedding, agg_w1, agg_w3, ws_session, adj_all, num_weight, ws_n1,
        ws_emb, ws_sw1, ws_w3t, ws_n2, ws_nw1);

    // fused: mode1 (75) + mode0 (7) + local_agg (1) per batch
    main_kernel<0><<<dim3(83, BATCH), 256, 0, stream>>>(
        inputs, adj, embedding, a_local, ws_n1, ws_n2, ws_nw0, ws_nw1,
        ws_emb, ws_sw1, agg_w1, agg_w2, ws_w3t,
        nullptr, nullptr, ws_out0, ws_out1, out);

    // mode2: hop-1 weights, self=out0, neigh=out1, += h_local in d_out
    main_kernel<2><<<dim3(7, BATCH), 256, 0, stream>>>(
        inputs, adj, embedding, a_local, ws_n1, ws_n2, ws_nw0, ws_nw1,
        ws_emb, ws_sw1, agg_w1, agg_w2, ws_w3t,
        ws_out0, ws_out1, nullptr, nullptr, out);
}